// Round 6
// baseline (526.965 us; speedup 1.0000x reference)
//
#include <hip/hip_runtime.h>
#include <cstdint>

#define NCOLS  696     // 16 + 120 + 560 subsets of size <= 3, bitmask order
#define BLOCK  64      // one wave per block
#define ROWS   64      // rows per block: lane r owns row blockIdx*64 + r
#define NCHUNK 22      // 22 chunks x 32 cols = 704 (last chunk: 24 real cols)
#define CHUNK  32
#define NPAD   (NCHUNK * CHUNK)

typedef float v4f __attribute__((ext_vector_type(4)));

// Branchless uniform descriptor (i | j<<4 | h<<8):
//   res = sel(sel(I_h, I_j), sel(I_j, I_i))
//   triple {i,j,h}: exactly the reference (L=pair{j,h}, R=pair{i,j})
//   pair   {j,h} -> (j,h,h): L=sel(I_h,I_h)=I_h, R=pair{j,h}; sel(I_h,pair)=pair (fixed pt)
//   single {h}   -> (h,h,h): res = I_h
// Validated absmax=0 on HW in rounds 1/4/5. Emission order = bitmask order.
struct alignas(16) Desc { uint32_t d[NPAD]; };
constexpr Desc make_desc() {
    Desc t{};
    int p = 0;
    for (int h = 0; h < 16; ++h) {
        t.d[p++] = (uint32_t)(h | (h << 4) | (h << 8));
        for (int j = 0; j < h; ++j) {
            t.d[p++] = (uint32_t)(j | (h << 4) | (h << 8));
            for (int i = 0; i < j; ++i)
                t.d[p++] = (uint32_t)(i | (j << 4) | (h << 8));
        }
    }
    for (; p < NPAD; ++p) t.d[p] = 0;   // padding cols: computed, never stored
    return t;
}
__constant__ Desc g_desc = make_desc();

// Tie-exact select. cur uses the sum proxy: RN(0.5l+0.5u) = 0.5*RN(l+u)
// exactly, so ==/> match the NumPy fp32 reference bit-for-bit.
__device__ __forceinline__ float2 selpair(float2 L, float2 R) {
    float curL = __fadd_rn(L.x, L.y);
    float curR = __fadd_rn(R.x, R.y);
    float bL = __fadd_rn(__fmul_rn(0.2f, L.x), __fmul_rn(0.8f, L.y));
    float bR = __fadd_rn(__fmul_rn(0.2f, R.x), __fmul_rn(0.8f, R.y));
    bool choose_right = (curL == curR) ? (bL > bR) : (curL > curR);
    return choose_right ? R : L;
}

// lane = row: descriptor stream is wave-uniform (scalar), compute is pure
// VALU, stores are coalesced via an LDS transpose tile. No barriers.
__global__ __launch_bounds__(BLOCK) void minint_kernel(
    const float* __restrict__ xl, const float* __restrict__ xu,
    float* __restrict__ out, int batch)
{
    __shared__ float2 iv[16 * 64];     // iv[i*64 + r]: transposed intervals
    __shared__ float2 st[CHUNK * 64];  // st[c*64 + ((r+c)&63)]: swizzled tile
    const int r = threadIdx.x;
    const size_t row = (size_t)blockIdx.x * ROWS + r;

    // Load this lane's row (16 intervals) and scatter transposed into LDS.
    const float4* pl = (const float4*)(xl + row * 16);
    const float4* pu = (const float4*)(xu + row * 16);
    float4 a0 = pl[0], a1 = pl[1], a2 = pl[2], a3 = pl[3];
    float4 b0 = pu[0], b1 = pu[1], b2 = pu[2], b3 = pu[3];
    iv[ 0*64 + r] = make_float2(a0.x, b0.x);
    iv[ 1*64 + r] = make_float2(a0.y, b0.y);
    iv[ 2*64 + r] = make_float2(a0.z, b0.z);
    iv[ 3*64 + r] = make_float2(a0.w, b0.w);
    iv[ 4*64 + r] = make_float2(a1.x, b1.x);
    iv[ 5*64 + r] = make_float2(a1.y, b1.y);
    iv[ 6*64 + r] = make_float2(a1.z, b1.z);
    iv[ 7*64 + r] = make_float2(a1.w, b1.w);
    iv[ 8*64 + r] = make_float2(a2.x, b2.x);
    iv[ 9*64 + r] = make_float2(a2.y, b2.y);
    iv[10*64 + r] = make_float2(a2.z, b2.z);
    iv[11*64 + r] = make_float2(a2.w, b2.w);
    iv[12*64 + r] = make_float2(a3.x, b3.x);
    iv[13*64 + r] = make_float2(a3.y, b3.y);
    iv[14*64 + r] = make_float2(a3.z, b3.z);
    iv[15*64 + r] = make_float2(a3.w, b3.w);
    // same-wave produce->consume: in-order DS pipe, no barrier needed

    const size_t row0 = (size_t)blockIdx.x * ROWS;
    float* outl = out + row0 * NCOLS;
    float* outu = out + (size_t)batch * NCOLS + row0 * NCOLS;

    int C = 0;
    for (int ch = 0; ch < NCHUNK; ++ch, C += CHUNK) {
        // Compute 32 columns for this lane's row into the swizzled tile.
        #pragma unroll 4
        for (int c = 0; c < CHUNK; ++c) {
            uint32_t d = g_desc.d[C + c];            // wave-uniform scalar
            float2 Ii = iv[(d & 15u) * 64 + r];
            float2 Ij = iv[((d >> 4) & 15u) * 64 + r];
            float2 Ih = iv[((d >> 8) & 15u) * 64 + r];
            float2 res = selpair(selpair(Ih, Ij), selpair(Ij, Ii));
            st[c * 64 + ((r + c) & 63)] = res;
        }
        // Flush tile: lane -> (row rr, col-quad cq); each store = 16B, 8
        // ascending lanes form a 128B contiguous run per row. Row stride
        // 2784B; 64-row group = 1392 full cache lines (line-aligned).
        const int ncq = (ch == NCHUNK - 1) ? 6 : 8;  // last chunk: 24 cols
        const int cq = r & 7;
        #pragma unroll
        for (int q = 0; q < 8; ++q) {
            const int rr = (r >> 3) + q * 8;
            if (cq < ncq) {
                const int c0 = cq * 4;
                float2 e0 = st[(c0 + 0) * 64 + ((rr + c0 + 0) & 63)];
                float2 e1 = st[(c0 + 1) * 64 + ((rr + c0 + 1) & 63)];
                float2 e2 = st[(c0 + 2) * 64 + ((rr + c0 + 2) & 63)];
                float2 e3 = st[(c0 + 3) * 64 + ((rr + c0 + 3) & 63)];
                v4f vl = { e0.x, e1.x, e2.x, e3.x };
                v4f vu = { e0.y, e1.y, e2.y, e3.y };
                const size_t off = (size_t)rr * NCOLS + (C + c0);
                __builtin_nontemporal_store(vl, (v4f*)(outl + off));
                __builtin_nontemporal_store(vu, (v4f*)(outu + off));
            }
        }
        // next chunk's tile writes ordered after these reads by the
        // per-wave in-order DS pipe; no barrier (single-wave block).
    }
}

extern "C" void kernel_launch(void* const* d_in, const int* in_sizes, int n_in,
                              void* d_out, int out_size, void* d_ws, size_t ws_size,
                              hipStream_t stream) {
    const float* xl = (const float*)d_in[0];
    const float* xu = (const float*)d_in[1];
    float* out = (float*)d_out;
    const int batch = in_sizes[0] / 16;          // 65536
    const int grid  = batch / ROWS;              // 1024 blocks x 1 wave
    minint_kernel<<<grid, BLOCK, 0, stream>>>(xl, xu, out, batch);
}